// Round 3
// baseline (176.388 us; speedup 1.0000x reference)
//
#include <hip/hip_runtime.h>
#include <hip/hip_bf16.h>
#include <math.h>

// Problem constants (from reference setup_inputs)
#define BS 4
#define C  3
#define D  8
#define K  10
#define K1 11
#define H  128
#define W  128
#define HW (H*W)

// One block per contiguous 64KB output plane (b, oc, di); oc = k*6 + j.
// j=0: heat (separable Gaussian, norm computed in-block via LDS)
// j=1,2: constant splat (dx, dy)
// j=3..5: deformed image channel = constant-shift bilinear blend of source.
// All stores walk the plane linearly (fill-like pattern).
__global__ __launch_bounds__(256) void memb_plane_kernel(
    const float* __restrict__ src,
    const float* __restrict__ kpd,
    const float* __restrict__ kps,
    float* __restrict__ out)
{
    const int p   = blockIdx.x;        // 0 .. 2111
    const int b   = p / (66 * D);
    const int rem = p % (66 * D);
    const int oc  = rem >> 3;          // /D
    const int di  = rem & (D - 1);
    const int k   = oc / 6;
    const int j   = oc % 6;
    const int tid = threadIdx.x;

    float* op = out + (size_t)p * HW;

    float kx = 0.f, ky = 0.f, dxv = 0.f, dyv = 0.f;
    if (k > 0) {
        int kidx = (b * D + di) * K + (k - 1);
        kx  = kpd[kidx * 2 + 0];
        ky  = kpd[kidx * 2 + 1];
        dxv = kps[kidx * 2 + 0] - kx;
        dyv = kps[kidx * 2 + 1] - ky;
    }

    if (j == 1 || j == 2) {           // constant planes
        float val = (j == 1) ? dxv : dyv;
        float4 v4 = make_float4(val, val, val, val);
        #pragma unroll
        for (int it = 0; it < 16; it++)
            ((float4*)op)[it * 256 + tid] = v4;
        return;
    }

    if (j == 0) {                     // heatmap plane
        if (k == 0) {                 // background: zeros
            float4 z = make_float4(0.f, 0.f, 0.f, 0.f);
            #pragma unroll
            for (int it = 0; it < 16; it++)
                ((float4*)op)[it * 256 + tid] = z;
            return;
        }
        __shared__ float gx[128], gy[128], red[2];
        if (tid < 128) {
            float c = (float)tid * (2.0f / 127.0f) - 1.0f - kx;
            gx[tid] = __expf(-50.0f * c * c);
        } else {
            int i = tid - 128;
            float c = (float)i * (2.0f / 127.0f) - 1.0f - ky;
            gy[i] = __expf(-50.0f * c * c);
        }
        __syncthreads();
        if (tid < 64) {
            float v = gx[tid] + gx[tid + 64];
            #pragma unroll
            for (int o = 32; o > 0; o >>= 1) v += __shfl_down(v, o, 64);
            if (tid == 0) red[0] = v;
        } else if (tid < 128) {
            int l = tid - 64;
            float v = gy[l] + gy[l + 64];
            #pragma unroll
            for (int o = 32; o > 0; o >>= 1) v += __shfl_down(v, o, 64);
            if (l == 0) red[1] = v;
        }
        __syncthreads();
        float nrm = 1.0f / (red[0] * red[1]);
        #pragma unroll 4
        for (int it = 0; it < 16; it++) {
            int ch = it * 256 + tid;
            int hi = ch >> 5;
            int wi = (ch & 31) << 2;
            float g = nrm * gy[hi];
            float4 gxv = *(const float4*)(gx + wi);   // LDS, 16B-aligned
            ((float4*)op)[ch] = make_float4(g * gxv.x, g * gxv.y,
                                            g * gxv.z, g * gxv.w);
        }
        return;
    }

    // j in {3,4,5}: deformed image channel ci = j-3.
    // px = wi + ox, py = hi + oy with plane-constant ox, oy -> constant
    // bilinear weights; translated window with zero padding.
    const int ci = j - 3;
    float ox = dxv * 63.5f;
    float oy = dyv * 63.5f;
    float fox = floorf(ox), foy = floorf(oy);
    int bcol = (int)fox, arow = (int)foy;
    float wx1 = ox - fox, wx0 = 1.0f - wx1;
    float wy1 = oy - foy, wy0 = 1.0f - wy1;
    const float* sp = src + ((size_t)b * C + ci) * HW;

    #pragma unroll 4
    for (int it = 0; it < 16; it++) {
        int ch = it * 256 + tid;
        int hi = ch >> 5;
        int wi = (ch & 31) << 2;
        int y0 = hi + arow, y1 = y0 + 1;
        int col0 = wi + bcol;
        float vy0 = (y0 >= 0 && y0 < H) ? wy0 : 0.0f;
        float vy1 = (y1 >= 0 && y1 < H) ? wy1 : 0.0f;
        int cy0 = min(max(y0, 0), H - 1);
        int cy1 = min(max(y1, 0), H - 1);
        const float* r0 = sp + cy0 * W;
        const float* r1 = sp + cy1 * W;
        float s0[5], s1[5];
        #pragma unroll
        for (int e = 0; e < 5; e++) {
            int c = col0 + e;
            float vm = (c >= 0 && c < W) ? 1.0f : 0.0f;
            int cc = min(max(c, 0), W - 1);
            s0[e] = r0[cc] * vm;
            s1[e] = r1[cc] * vm;
        }
        float4 o4;
        o4.x = vy0 * (wx0 * s0[0] + wx1 * s0[1]) + vy1 * (wx0 * s1[0] + wx1 * s1[1]);
        o4.y = vy0 * (wx0 * s0[1] + wx1 * s0[2]) + vy1 * (wx0 * s1[1] + wx1 * s1[2]);
        o4.z = vy0 * (wx0 * s0[2] + wx1 * s0[3]) + vy1 * (wx0 * s1[2] + wx1 * s1[3]);
        o4.w = vy0 * (wx0 * s0[3] + wx1 * s0[4]) + vy1 * (wx0 * s1[3] + wx1 * s1[4]);
        ((float4*)op)[ch] = o4;
    }
}

extern "C" void kernel_launch(void* const* d_in, const int* in_sizes, int n_in,
                              void* d_out, int out_size, void* d_ws, size_t ws_size,
                              hipStream_t stream) {
    const float* src = (const float*)d_in[0];   // (4,3,1,128,128)
    const float* kpd = (const float*)d_in[1];   // (4,8,10,2)
    const float* kps = (const float*)d_in[2];   // (4,8,10,2)
    float* out = (float*)d_out;                 // (4,66,8,128,128)

    const int planes = BS * 66 * D;             // 2112
    memb_plane_kernel<<<planes, 256, 0, stream>>>(src, kpd, kps, out);
}

// Round 5
// 156.897 us; speedup vs baseline: 1.1242x; 1.1242x over previous
//
#include <hip/hip_runtime.h>
#include <hip/hip_bf16.h>
#include <math.h>

// Problem constants (from reference setup_inputs)
#define BS 4
#define C  3
#define D  8
#define K  10
#define K1 11
#define H  128
#define W  128
#define HW (H*W)

// Kernel 1: per-(b,d,k) heatmap normalization constant.
// heat = exp(-50*((x-kx)^2+(y-ky)^2)); sum over (h,w) is separable:
// sum = (sum_x exp(-50*(x-kx)^2)) * (sum_y exp(-50*(y-ky)^2)).
// One 64-thread wave per (b,d,k); writes 1/sum to norm[].
__global__ void memb_norm_kernel(const float* __restrict__ kpd,
                                 float* __restrict__ norm) {
    int idx = blockIdx.x;              // 0 .. BS*D*K-1
    float kx = kpd[idx * 2 + 0];
    float ky = kpd[idx * 2 + 1];
    int lane = threadIdx.x;            // 0..63, one wave
    float sx = 0.f, sy = 0.f;
    #pragma unroll
    for (int j = lane; j < W; j += 64) {
        float coord = (float)j * (2.0f / 127.0f) - 1.0f;
        float ddx = coord - kx;
        float ddy = coord - ky;
        sx += __expf(-50.0f * ddx * ddx);
        sy += __expf(-50.0f * ddy * ddy);
    }
    #pragma unroll
    for (int o = 32; o > 0; o >>= 1) {
        sx += __shfl_down(sx, o, 64);
        sy += __shfl_down(sy, o, 64);
    }
    if (lane == 0) norm[idx] = 1.0f / (sx * sy);
}

// Kernel 2: one thread per (b, di, k, hi, wi). Computes the 6 output
// channels for that keypoint slot: heat, dx, dy, 3 bilinear samples.
// Output layout: (bs, 66, d, h, w), oc = k*6 + j.
__global__ void memb_main_kernel(const float* __restrict__ src,
                                 const float* __restrict__ kpd,
                                 const float* __restrict__ kps,
                                 const float* __restrict__ norm,
                                 float* __restrict__ out) {
    int t = blockIdx.x * blockDim.x + threadIdx.x;
    const int total = BS * D * K1 * HW;
    if (t >= total) return;

    int wi = t & (W - 1);
    int hi = (t >> 7) & (H - 1);
    int k  = (t >> 14) % K1;
    int r  = (t >> 14) / K1;   // b*D + di
    int di = r & (D - 1);
    int b  = r >> 3;

    float x = (float)wi * (2.0f / 127.0f) - 1.0f;
    float y = (float)hi * (2.0f / 127.0f) - 1.0f;

    float heat = 0.f, dx = 0.f, dy = 0.f;
    if (k > 0) {
        int kidx = r * K + (k - 1);
        float kx  = kpd[kidx * 2 + 0];
        float kyv = kpd[kidx * 2 + 1];
        dx = kps[kidx * 2 + 0] - kx;
        dy = kps[kidx * 2 + 1] - kyv;
        float ex = x - kx, ey = y - kyv;
        heat = __expf(-50.0f * (ex * ex + ey * ey)) * norm[kidx];
    }

    // Bilinear sample of source at (x+dx, y+dy), align_corners=True, zero pad.
    float px = (x + dx + 1.0f) * 63.5f;
    float py = (y + dy + 1.0f) * 63.5f;
    float fx0 = floorf(px), fy0 = floorf(py);
    int x0 = (int)fx0, y0 = (int)fy0;
    int x1 = x0 + 1,   y1 = y0 + 1;
    float wx1 = px - fx0, wy1 = py - fy0;
    float wx0 = 1.0f - wx1, wy0 = 1.0f - wy1;

    float vx0 = (x0 >= 0 && x0 <= W - 1) ? 1.0f : 0.0f;
    float vx1 = (x1 >= 0 && x1 <= W - 1) ? 1.0f : 0.0f;
    float vy0 = (y0 >= 0 && y0 <= H - 1) ? 1.0f : 0.0f;
    float vy1 = (y1 >= 0 && y1 <= H - 1) ? 1.0f : 0.0f;

    int cx0 = min(max(x0, 0), W - 1), cx1 = min(max(x1, 0), W - 1);
    int cy0 = min(max(y0, 0), H - 1), cy1 = min(max(y1, 0), H - 1);

    float w00 = wx0 * wy0 * vx0 * vy0;
    float w10 = wx1 * wy0 * vx1 * vy0;
    float w01 = wx0 * wy1 * vx0 * vy1;
    float w11 = wx1 * wy1 * vx1 * vy1;

    const float* sb = src + (size_t)b * C * HW;
    int o00 = cy0 * W + cx0, o10 = cy0 * W + cx1;
    int o01 = cy1 * W + cx0, o11 = cy1 * W + cx1;

    float v[C];
    #pragma unroll
    for (int ci = 0; ci < C; ci++) {
        const float* sc = sb + ci * HW;
        v[ci] = w00 * sc[o00] + w10 * sc[o10] + w01 * sc[o01] + w11 * sc[o11];
    }

    // out flat index: ((b*66 + k*6 + j)*D + di)*HW + hi*W + wi
    const size_t cs = (size_t)D * HW;  // stride for one output channel
    size_t base = ((size_t)(b * 66 + k * 6) * D + di) * HW + hi * W + wi;
    out[base + 0 * cs] = heat;
    out[base + 1 * cs] = dx;
    out[base + 2 * cs] = dy;
    out[base + 3 * cs] = v[0];
    out[base + 4 * cs] = v[1];
    out[base + 5 * cs] = v[2];
}

extern "C" void kernel_launch(void* const* d_in, const int* in_sizes, int n_in,
                              void* d_out, int out_size, void* d_ws, size_t ws_size,
                              hipStream_t stream) {
    const float* src = (const float*)d_in[0];   // (4,3,1,128,128)
    const float* kpd = (const float*)d_in[1];   // (4,8,10,2)
    const float* kps = (const float*)d_in[2];   // (4,8,10,2)
    float* out  = (float*)d_out;                // (4,66,8,128,128)
    float* norm = (float*)d_ws;                 // 320 floats

    memb_norm_kernel<<<BS * D * K, 64, 0, stream>>>(kpd, norm);

    const int total = BS * D * K1 * HW;         // 5,767,168
    const int block = 256;
    const int grid = (total + block - 1) / block;
    memb_main_kernel<<<grid, block, 0, stream>>>(src, kpd, kps, norm, out);
}